// Round 9
// baseline (240.388 us; speedup 1.0000x reference)
//
#include <hip/hip_runtime.h>
#include <hip/hip_bf16.h>

// QuantisedMonDEQ: n=512, d=784, B=128, C=10. All inputs/outputs float32.
// z_{t+1} = relu(0.5 z + 0.5 (Wq z + Ux)), ~40 iters; logits = z*^T Wc^T + bc.
//
// TWO dispatches: maxabs (192 blocks) then ONE fused solve (8 blocks x 512).
// Each solve block owns 16 batch cols and holds ALL of Q = rint(W/sW) (int8,
// exact) in registers: A[4][8] i32x4 = 128 VGPR/lane = 256 KB/block.
// z as Q-ish fixed point v = round(y*32767), y = z/16, split into hi/lo int8
// planes stored in MFMA-B fragment order [kc][quad][m][16B] -> LDS reads are
// addr = 16*lane (conflict-free), writes 2-way (free).
//   Q.v = 256*(Q.hi) + Q.lo' + 128*rowsum(Q),  rowsum folded into C.
// Iters: first 25 hi-plane only, last 12 both planes (~fp32 z).
// Ux computed in-kernel via bf16 MFMA (Uq exact bf16, x split hi/lo); its
// D-layout == solve acch layout -> Ux/C never leave registers. Logits fused.

#define N_DIM 512
#define D_DIM 784
#define B_DIM 128
#define C_DIM 10
#define QMAX 127.0f
#define TOTAL_ITERS 38
#define LO_ITERS 12
#define MT 4            // 16-row M-tiles per wave (8 waves x 64 rows)

typedef int    i32x4  __attribute__((ext_vector_type(4)));
typedef float  f32x4  __attribute__((ext_vector_type(4)));
typedef __bf16 bf16x8 __attribute__((ext_vector_type(8)));

__device__ __forceinline__ float pscale64(const float* __restrict__ p) {
    float m = 0.0f;
#pragma unroll 16
    for (int i = 0; i < 64; ++i) m = fmaxf(m, p[i]);
    return m * (1.0f / QMAX);
}

// ---------------- per-block partial max|.| ----------------
__global__ void maxabs_kernel(const float* __restrict__ W,
                              const float* __restrict__ U,
                              const float* __restrict__ b,
                              float* __restrict__ partials) {
    const float4* src;
    int n4;
    if (blockIdx.y == 0)      { src = (const float4*)W; n4 = N_DIM * N_DIM / 4; }
    else if (blockIdx.y == 1) { src = (const float4*)U; n4 = N_DIM * D_DIM / 4; }
    else                      { src = (const float4*)b; n4 = N_DIM / 4; }
    float m = 0.0f;
    for (int i = blockIdx.x * blockDim.x + threadIdx.x; i < n4; i += gridDim.x * blockDim.x) {
        float4 v = src[i];
        m = fmaxf(m, fmaxf(fmaxf(fabsf(v.x), fabsf(v.y)), fmaxf(fabsf(v.z), fabsf(v.w))));
    }
    __shared__ float red[256];
    red[threadIdx.x] = m;
    __syncthreads();
    for (int s = 128; s > 0; s >>= 1) {
        if (threadIdx.x < s) red[threadIdx.x] = fmaxf(red[threadIdx.x], red[threadIdx.x + s]);
        __syncthreads();
    }
    if (threadIdx.x == 0) partials[blockIdx.y * 64 + blockIdx.x] = red[0];
}

// pack 4 y-values into hi (and optionally lo) int8-plane dwords
__device__ __forceinline__ void pack_planes(float y0, float y1, float y2, float y3,
                                            unsigned* hi, unsigned* lo) {
    int p01, p23;
    asm("v_cvt_pknorm_i16_f32 %0, %1, %2" : "=v"(p01) : "v"(y0), "v"(y1));
    asm("v_cvt_pknorm_i16_f32 %0, %1, %2" : "=v"(p23) : "v"(y2), "v"(y3));
    *hi = __builtin_amdgcn_perm((unsigned)p23, (unsigned)p01, 0x07050301u);
    *lo = __builtin_amdgcn_perm((unsigned)p23, (unsigned)p01, 0x06040200u) ^ 0x80808080u;
}

// ---------------- fully fused quant + uxT + solve + logits ----------------
__global__ __launch_bounds__(512, 2) void solve_kernel(const float* __restrict__ W,
                                                       const float* __restrict__ U,
                                                       const float* __restrict__ b,
                                                       const float* __restrict__ x,
                                                       const float* __restrict__ Wc,
                                                       const float* __restrict__ bc,
                                                       const float* __restrict__ partials,
                                                       float* __restrict__ out) {
    __shared__ signed char zh[2][8192];   // [buf][kc*1024 + quad*256 + m*16 + j]
    __shared__ signed char zl[2][8192];
    __shared__ __bf16 xhS[12800];         // [kc25][quad4][m16][8]
    __shared__ __bf16 xlS[12800];
    __shared__ float rsS[N_DIM];
    __shared__ float bqS[N_DIM];
    __shared__ float WcS[C_DIM][N_DIM];
    __shared__ float redS[32][16][C_DIM];

    const int t = threadIdx.x;
    const int wave = t >> 6, lane = t & 63;
    const int m = lane & 15, quad = lane >> 4;
    const int c0 = blockIdx.x * 16;
    const int rowbase = wave * 64;

    const float sW = pscale64(partials);
    const float sU = pscale64(partials + 64);
    const float sb = pscale64(partials + 128);
    const float invW = 1.0f / sW, invU = 1.0f / sU;
    const float sWv = sW * (16.0f / 32767.0f);   // z per unit v
    const float K16 = 0.03125f;                  // 0.5/16
    const float KH = K16 * sWv * 256.0f;
    const float KL = K16 * sWv;
    const float KL128 = KL * 128.0f;

    // ---- stage x (hi/lo bf16, MFMA-B layout), bq, Wc ----
    for (int rr = 0; rr < 16; ++rr) {
        for (int k = t; k < D_DIM; k += 512) {
            float xv = x[(c0 + rr) * D_DIM + k];
            __bf16 h = (__bf16)xv;
            int idx = ((k >> 5) * 4 + ((k >> 3) & 3)) * 128 + rr * 8 + (k & 7);
            xhS[idx] = h;
            xlS[idx] = (__bf16)(xv - (float)h);
        }
    }
    for (int i = t; i < 256; i += 512) {   // zero pad k in [784,800)
        int k = 784 + (i & 15), rr = i >> 4;
        int idx = ((k >> 5) * 4 + ((k >> 3) & 3)) * 128 + rr * 8 + (k & 7);
        xhS[idx] = (__bf16)0.0f;
        xlS[idx] = (__bf16)0.0f;
    }
    bqS[t] = rintf(b[t] / sb) * sb;
    for (int i = t; i < C_DIM * N_DIM; i += 512) (&WcS[0][0])[i] = Wc[i];
    __syncthreads();

    // ---- uxT via bf16 MFMA: uacc[ti] D(row=rowbase+ti*16+quad*4+r, col=c0+m) ----
    f32x4 uacc[MT] = {};
#pragma unroll 2
    for (int kc = 0; kc < 25; ++kc) {
        bf16x8 bh = *(const bf16x8*)&xhS[kc * 512 + quad * 128 + m * 8];
        bf16x8 bl = *(const bf16x8*)&xlS[kc * 512 + quad * 128 + m * 8];
#pragma unroll
        for (int ti = 0; ti < MT; ++ti) {
            bf16x8 au;
            if (kc < 24 || quad < 2) {
                const float* up = U + (rowbase + ti * 16 + m) * D_DIM + kc * 32 + quad * 8;
                float4 u0 = *(const float4*)up;
                float4 u1 = *(const float4*)(up + 4);
                au[0] = (__bf16)rintf(u0.x * invU); au[1] = (__bf16)rintf(u0.y * invU);
                au[2] = (__bf16)rintf(u0.z * invU); au[3] = (__bf16)rintf(u0.w * invU);
                au[4] = (__bf16)rintf(u1.x * invU); au[5] = (__bf16)rintf(u1.y * invU);
                au[6] = (__bf16)rintf(u1.z * invU); au[7] = (__bf16)rintf(u1.w * invU);
            } else {
#pragma unroll
                for (int j = 0; j < 8; ++j) au[j] = (__bf16)0.0f;
            }
            uacc[ti] = __builtin_amdgcn_mfma_f32_16x16x32_bf16(au, bh, uacc[ti], 0, 0, 0);
            uacc[ti] = __builtin_amdgcn_mfma_f32_16x16x32_bf16(au, bl, uacc[ti], 0, 0, 0);
        }
    }

    // ---- W quant -> register-resident A frags + exact rowsum (float) ----
    i32x4 A[MT][8];
    float rsum[MT] = {0.f, 0.f, 0.f, 0.f};
#pragma unroll
    for (int ti = 0; ti < MT; ++ti) {
#pragma unroll
        for (int kc = 0; kc < 8; ++kc) {
            const float* wp = W + (rowbase + ti * 16 + m) * N_DIM + kc * 64 + quad * 16;
            i32x4 av;
#pragma unroll
            for (int s = 0; s < 4; ++s) {
                float4 w4 = *(const float4*)(wp + s * 4);
                float f0 = rintf(w4.x * invW), f1 = rintf(w4.y * invW);
                float f2 = rintf(w4.z * invW), f3 = rintf(w4.w * invW);
                rsum[ti] += (f0 + f1) + (f2 + f3);
                av[s] = ((int)f0 & 255) | (((int)f1 & 255) << 8) |
                        (((int)f2 & 255) << 16) | ((int)f3 << 24);
            }
            A[ti][kc] = av;
        }
    }
#pragma unroll
    for (int ti = 0; ti < MT; ++ti) {
        rsum[ti] += __shfl_xor(rsum[ti], 16);
        rsum[ti] += __shfl_xor(rsum[ti], 32);
        if (quad == 0) rsS[rowbase + ti * 16 + m] = rsum[ti];
        asm volatile("" : "+v"(A[ti][0]), "+v"(A[ti][1]), "+v"(A[ti][2]), "+v"(A[ti][3]),
                          "+v"(A[ti][4]), "+v"(A[ti][5]), "+v"(A[ti][6]), "+v"(A[ti][7]));
    }
    __syncthreads();

    // ---- finalize C (Ux + rowsum fold, /16 domain) + z1 = relu(0.5 Ux) ----
    float yv[MT][4], Cf[MT][4];
#pragma unroll
    for (int ti = 0; ti < MT; ++ti) {
        const int row0 = rowbase + ti * 16 + quad * 4;
#pragma unroll
        for (int r = 0; r < 4; ++r) {
            float Uxval = fmaf(sU, uacc[ti][r], bqS[row0 + r]);
            Cf[ti][r] = fmaf(KL128, rsS[row0 + r], K16 * Uxval);
            yv[ti][r] = fmaxf(K16 * Uxval, 0.0f);
        }
        unsigned hw, lw;
        pack_planes(yv[ti][0], yv[ti][1], yv[ti][2], yv[ti][3], &hw, &lw);
        *(unsigned*)&zh[0][wave * 1024 + ti * 256 + m * 16 + quad * 4] = hw;
    }
    __syncthreads();

    // ---- fixed-point loop ----
    int cur = 0;
    for (int it = 1; it < TOTAL_ITERS; ++it) {
        const bool lo  = (it >= TOTAL_ITERS - LO_ITERS);
        const bool wlo = (it >= TOTAL_ITERS - LO_ITERS - 1);
        i32x4 acch[MT] = {};
        i32x4 accl[MT] = {};
#pragma unroll
        for (int kc = 0; kc < 8; ++kc) {
            i32x4 bh = *(const i32x4*)&zh[cur][kc * 1024 + quad * 256 + m * 16];
#pragma unroll
            for (int ti = 0; ti < MT; ++ti)
                acch[ti] = __builtin_amdgcn_mfma_i32_16x16x64_i8(A[ti][kc], bh, acch[ti], 0, 0, 0);
        }
        if (lo) {
#pragma unroll
            for (int kc = 0; kc < 8; ++kc) {
                i32x4 bl = *(const i32x4*)&zl[cur][kc * 1024 + quad * 256 + m * 16];
#pragma unroll
                for (int ti = 0; ti < MT; ++ti)
                    accl[ti] = __builtin_amdgcn_mfma_i32_16x16x64_i8(A[ti][kc], bl, accl[ti], 0, 0, 0);
            }
        }
        const int nxt = cur ^ 1;
#pragma unroll
        for (int ti = 0; ti < MT; ++ti) {
#pragma unroll
            for (int r = 0; r < 4; ++r) {
                float base = lo ? fmaf(KL, (float)accl[ti][r], Cf[ti][r]) : Cf[ti][r];
                float u = fmaf(KH, (float)acch[ti][r], base);
                yv[ti][r] = fmaxf(fmaf(0.5f, yv[ti][r], u), 0.0f);
            }
            unsigned hw, lw;
            pack_planes(yv[ti][0], yv[ti][1], yv[ti][2], yv[ti][3], &hw, &lw);
            const int wr = wave * 1024 + ti * 256 + m * 16 + quad * 4;
            *(unsigned*)&zh[nxt][wr] = hw;
            if (wlo) *(unsigned*)&zl[nxt][wr] = lw;
        }
        __syncthreads();
        cur = nxt;
    }

    // ---- fused logits from register y (z = 16 y) ----
    {
        float p[C_DIM];
#pragma unroll
        for (int cl = 0; cl < C_DIM; ++cl) p[cl] = 0.0f;
#pragma unroll
        for (int ti = 0; ti < MT; ++ti) {
            const int row0 = rowbase + ti * 16 + quad * 4;
#pragma unroll
            for (int r = 0; r < 4; ++r) {
                float zv = 16.0f * yv[ti][r];
#pragma unroll
                for (int cl = 0; cl < C_DIM; ++cl)
                    p[cl] += zv * WcS[cl][row0 + r];
            }
        }
        const int grp = wave * 4 + quad;
#pragma unroll
        for (int cl = 0; cl < C_DIM; ++cl) redS[grp][m][cl] = p[cl];
        __syncthreads();
        for (int s = 16; s > 0; s >>= 1) {
            if (grp < s) {
#pragma unroll
                for (int cl = 0; cl < C_DIM; ++cl)
                    redS[grp][m][cl] += redS[grp + s][m][cl];
            }
            __syncthreads();
        }
        if (t < 16 * C_DIM)
            out[(c0 + (t & 15)) * C_DIM + (t >> 4)] = redS[0][t & 15][t >> 4] + bc[t >> 4];
    }
}

extern "C" void kernel_launch(void* const* d_in, const int* in_sizes, int n_in,
                              void* d_out, int out_size, void* d_ws, size_t ws_size,
                              hipStream_t stream) {
    const float* W  = (const float*)d_in[0];
    const float* U  = (const float*)d_in[1];
    const float* b  = (const float*)d_in[2];
    const float* x  = (const float*)d_in[3];
    const float* Wc = (const float*)d_in[4];
    const float* bc = (const float*)d_in[5];
    float* out = (float*)d_out;

    float* partials = (float*)d_ws;   // 3*64 floats

    maxabs_kernel<<<dim3(64, 3), 256, 0, stream>>>(W, U, b, partials);
    solve_kernel<<<8, 512, 0, stream>>>(W, U, b, x, Wc, bc, partials, out);
}